// Round 2
// baseline (831.645 us; speedup 1.0000x reference)
//
#include <hip/hip_runtime.h>
#include <hip/hip_bf16.h>
#include <stdint.h>

typedef unsigned short u16;
typedef unsigned int u32;
typedef __bf16 bf16x8 __attribute__((ext_vector_type(8)));
typedef float f32x4 __attribute__((ext_vector_type(4)));

#define M_ROWS 32768   // bs*seq
#define DIM    1024    // inp_dim
#define NPROJ  64
#define NBINS  20
#define FDIM   1280    // NPROJ*NBINS
#define EDIM   1024    // emb_dim

// round-to-nearest-even f32 -> bf16
__device__ __forceinline__ u16 f2bf(float f) {
    union { float f; u32 u; } v; v.f = f;
    return (u16)((v.u + 0x7FFFu + ((v.u >> 16) & 1u)) >> 16);
}

__device__ __forceinline__ float wave_sum(float v) {
    #pragma unroll
    for (int o = 32; o > 0; o >>= 1) v += __shfl_down(v, o, 64);
    return v;
}

// ---------------------------------------------------------------------------
// K1: normalize proj_weight rows, store TRANSPOSED k-major: wnt[k][j], fp32.
__global__ void k_norm_w(const float* __restrict__ w, float* __restrict__ wnt) {
    int j = blockIdx.x;
    int t = threadIdx.x;
    float4 v = ((const float4*)(w + (size_t)j * DIM))[t];
    float ss = v.x*v.x + v.y*v.y + v.z*v.z + v.w*v.w;
    ss = wave_sum(ss);
    __shared__ float red[4];
    if ((t & 63) == 0) red[t >> 6] = ss;
    __syncthreads();
    float rn = 1.0f / fmaxf(sqrtf(red[0] + red[1] + red[2] + red[3]), 1e-12f);
    int k = t * 4;
    wnt[(size_t)(k+0)*NPROJ + j] = v.x * rn;
    wnt[(size_t)(k+1)*NPROJ + j] = v.y * rn;
    wnt[(size_t)(k+2)*NPROJ + j] = v.z * rn;
    wnt[(size_t)(k+3)*NPROJ + j] = v.w * rn;
}

// ---------------------------------------------------------------------------
// K2: emb_weight fp32 -> bf16, same [EDIM][FDIM] layout.
__global__ void k_cvt(const float* __restrict__ s, u16* __restrict__ d) {
    int i = blockIdx.x * 256 + threadIdx.x;
    float4 v = ((const float4*)s)[i];
    ushort4 o; o.x = f2bf(v.x); o.y = f2bf(v.y); o.z = f2bf(v.z); o.w = f2bf(v.w);
    ((ushort4*)d)[i] = o;
}

// ---------------------------------------------------------------------------
// K3 (fused front-end): rnx + cosine-GEMM + RBF + top-4 + group-L2-norm -> z.
// 512 blocks x 256 threads. Block = 64 rows. Thread (r = t>>2, jset = (t&3)*16)
// owns 16 projection outputs for one row; iterates full K=1024.
//   x   staged per 64-k chunk in LDS (coalesced load, padded, broadcast read)
//   wnt read directly from global (k-major, 16KB/chunk, L1-merged dwordx4)
//   ss (row sum-squares) accumulated inline -> no separate rnx kernel
__global__ __launch_bounds__(256) void k_front(
        const float* __restrict__ x, const float* __restrict__ wnt,
        const float* __restrict__ mean, u16* __restrict__ z) {
    __shared__ float xs[64][66];   // 64 rows x 64 k, pad 66 -> conflict-free
    __shared__ float mlds[FDIM];
    int t = threadIdx.x;
    int row0 = blockIdx.x * 64;
    int r = t >> 2;                // local row 0..63
    int jset = (t & 3) * 16;       // 16 projs per thread

    for (int i = t; i < FDIM; i += 256) mlds[i] = mean[i];

    float acc[16] = {};
    float ss = 0.0f;

    for (int c = 0; c < 16; c++) {
        int k0 = c * 64;
        // stage x[row0..+63][k0..+63] coalesced: 1024 float4s, 4 per thread
        #pragma unroll
        for (int pass = 0; pass < 4; pass++) {
            int idx = t + pass * 256;          // 0..1023
            int sr = idx >> 4, skq = idx & 15;
            float4 v = *(const float4*)(x + (size_t)(row0 + sr) * DIM + k0 + skq * 4);
            float* dst = &xs[sr][skq * 4];
            dst[0] = v.x; dst[1] = v.y; dst[2] = v.z; dst[3] = v.w;
        }
        __syncthreads();
        const float* wbase = wnt + (size_t)k0 * NPROJ + jset;
        #pragma unroll 4
        for (int k = 0; k < 64; k++) {
            float xv = xs[r][k];
            const float4* wp = (const float4*)(wbase + (size_t)k * NPROJ);
            float4 w0 = wp[0], w1 = wp[1], w2 = wp[2], w3 = wp[3];
            ss += xv * xv;
            acc[0]  += xv * w0.x; acc[1]  += xv * w0.y; acc[2]  += xv * w0.z; acc[3]  += xv * w0.w;
            acc[4]  += xv * w1.x; acc[5]  += xv * w1.y; acc[6]  += xv * w1.z; acc[7]  += xv * w1.w;
            acc[8]  += xv * w2.x; acc[9]  += xv * w2.y; acc[10] += xv * w2.z; acc[11] += xv * w2.w;
            acc[12] += xv * w3.x; acc[13] += xv * w3.y; acc[14] += xv * w3.z; acc[15] += xv * w3.w;
        }
        __syncthreads();
    }

    float rn = 1.0f / fmaxf(sqrtf(ss), 1e-12f);
    size_t row = (size_t)(row0 + r);
    u32* zp = (u32*)(z + row * FDIM + jset * NBINS);   // 640 B contiguous/thread

    #pragma unroll
    for (int jj = 0; jj < 16; jj++) {
        int j = jset + jj;
        float pv = acc[jj] * rn;
        float act[NBINS];
        float top0 = -1e30f, top1 = -1e30f, top2 = -1e30f, top3 = -1e30f;
        #pragma unroll
        for (int b = 0; b < NBINS; b++) {
            float d = pv - mlds[j * NBINS + b];
            float a = __expf(-50.0f * d * d);   // 0.5/sigma2 = 50
            act[b] = a;
            if (a > top3) {
                if (a > top0)      { top3 = top2; top2 = top1; top1 = top0; top0 = a; }
                else if (a > top1) { top3 = top2; top2 = top1; top1 = a; }
                else if (a > top2) { top3 = top2; top2 = a; }
                else               { top3 = a; }
            }
        }
        float ssq = 0.0f;
        #pragma unroll
        for (int b = 0; b < NBINS; b++) {
            float a = (act[b] >= top3) ? act[b] : 0.0f;   // keep ties
            act[b] = a;
            ssq += a * a;
        }
        float rn2 = 1.0f / fmaxf(sqrtf(ssq), 1e-12f);
        #pragma unroll
        for (int i = 0; i < 10; i++) {
            u32 lo = f2bf(act[2*i] * rn2);
            u32 hi = f2bf(act[2*i+1] * rn2);
            zp[jj * 10 + i] = lo | (hi << 16);
        }
    }
}

// ---------------------------------------------------------------------------
// K4: GEMM2 bf16 MFMA: C[m][n] = sum_k A[m][k]*B[n][k]
// A = z [32768 x 1280], B = embW bf16 [1024 x 1280], C fp32 [32768 x 1024].
// 128x128 tile, BK=32, 4 waves 2x2, wave = 4x4 of 16x16x32 MFMA.
// Operands swapped (B as MFMA-A) so D rows map to n -> dwordx4 C stores.
// 1-D grid with XCD swizzle: bn fast within each XCD's 32-bm stripe.
__device__ __forceinline__ void gl_lds16(const void* g, void* l) {
    __builtin_amdgcn_global_load_lds(
        (const __attribute__((address_space(1))) void*)g,
        (__attribute__((address_space(3))) void*)l, 16, 0, 0);
}

__global__ __launch_bounds__(256) void k_gemm2(const u16* __restrict__ A,
                                               const u16* __restrict__ B,
                                               float* __restrict__ C) {
    const int K = FDIM, N = EDIM;
    __shared__ u16 As[128 * 32];
    __shared__ u16 Bs[128 * 32];
    int t = threadIdx.x;
    int lane = t & 63, wave = t >> 6;

    // XCD-aware swizzle: l%8 = XCD; within an XCD, bn varies fastest over an
    // 8-wide bn row so each 327KB A-tile gets its 8 reuses while L2-hot.
    int l = blockIdx.x;
    int xcd = l & 7;
    int s = l >> 3;
    int bn = (s & 7) * 128;
    int bm = ((xcd << 5) | (s >> 3)) * 128;

    int wm = (wave >> 1) * 64, wn = (wave & 1) * 64;
    int m16 = lane & 15, q = lane >> 4;

    f32x4 zero = {0.f, 0.f, 0.f, 0.f};
    f32x4 acc[4][4];
    #pragma unroll
    for (int i = 0; i < 4; i++)
        #pragma unroll
        for (int j = 0; j < 4; j++) acc[i][j] = zero;

    // staging: thread t -> row sr (0..63, +64), 8-elem chunk sc
    int sr = t >> 2;
    int sc = (t & 3) * 8;
    const u16* ga = A + (size_t)(bm + sr) * K + sc;
    const u16* gb = B + (size_t)(bn + sr) * K + sc;
    u16* la = &As[sr * 32 + sc];
    u16* lb = &Bs[sr * 32 + sc];

    for (int k0 = 0; k0 < K; k0 += 32) {
        gl_lds16(ga + k0,                 la);
        gl_lds16(ga + k0 + (size_t)64*K,  la + 64 * 32);
        gl_lds16(gb + k0,                 lb);
        gl_lds16(gb + k0 + (size_t)64*K,  lb + 64 * 32);
        __syncthreads();
        bf16x8 af[4], bfr[4];
        #pragma unroll
        for (int i = 0; i < 4; i++)
            af[i] = *(const bf16x8*)&As[(wm + i * 16 + m16) * 32 + q * 8];
        #pragma unroll
        for (int j = 0; j < 4; j++)
            bfr[j] = *(const bf16x8*)&Bs[(wn + j * 16 + m16) * 32 + q * 8];
        // D = mfma(Bfrag, Afrag): D "row" dim = n, "col" dim = m
        #pragma unroll
        for (int i = 0; i < 4; i++)
            #pragma unroll
            for (int j = 0; j < 4; j++)
                acc[i][j] = __builtin_amdgcn_mfma_f32_16x16x32_bf16(
                    bfr[j], af[i], acc[i][j], 0, 0, 0);
        __syncthreads();
    }
    // D layout: col(m) = lane&15, row(n) = q*4 + reg -> 4 consecutive n = dwordx4
    #pragma unroll
    for (int i = 0; i < 4; i++)
        #pragma unroll
        for (int j = 0; j < 4; j++) {
            int m = bm + wm + i * 16 + m16;
            int n = bn + wn + j * 16 + q * 4;
            *(float4*)&C[(size_t)m * N + n] = *(float4*)&acc[i][j];
        }
}

// ---------------------------------------------------------------------------
extern "C" void kernel_launch(void* const* d_in, const int* in_sizes, int n_in,
                              void* d_out, int out_size, void* d_ws, size_t ws_size,
                              hipStream_t stream) {
    const float* x    = (const float*)d_in[0];   // [32768][1024]
    const float* pw   = (const float*)d_in[1];   // [64][1024]
    const float* mean = (const float*)d_in[2];   // [64][20]
    const float* emb  = (const float*)d_in[3];   // [1024][1280]
    float* out = (float*)d_out;                  // [32768][1024] fp32

    char* ws = (char*)d_ws;
    u16*   z    = (u16*)(ws);                    // 83,886,080 B
    float* wnt  = (float*)(ws + 83886080);       //    262,144 B (k-major)
    u16*   embW = (u16*)(ws + 84148224);         //  2,621,440 B
    // total: 86,769,664 B

    k_norm_w<<<64, 256, 0, stream>>>(pw, wnt);
    k_cvt<<<(EDIM * FDIM / 4) / 256, 256, 0, stream>>>(emb, embW);
    k_front<<<M_ROWS / 64, 256, 0, stream>>>(x, wnt, mean, z);
    k_gemm2<<<(M_ROWS / 128) * (EDIM / 128), 256, 0, stream>>>(z, embW, out);
}

// Round 3
// 543.198 us; speedup vs baseline: 1.5310x; 1.5310x over previous
//
#include <hip/hip_runtime.h>
#include <hip/hip_bf16.h>
#include <stdint.h>

typedef unsigned short u16;
typedef unsigned int u32;
typedef __bf16 bf16x8 __attribute__((ext_vector_type(8)));
typedef float f32x4 __attribute__((ext_vector_type(4)));

#define M_ROWS 32768   // bs*seq
#define DIM    1024    // inp_dim
#define NPROJ  64
#define NBINS  20
#define FDIM   1280    // NPROJ*NBINS
#define EDIM   1024    // emb_dim

// round-to-nearest-even f32 -> bf16
__device__ __forceinline__ u16 f2bf(float f) {
    union { float f; u32 u; } v; v.f = f;
    return (u16)((v.u + 0x7FFFu + ((v.u >> 16) & 1u)) >> 16);
}

__device__ __forceinline__ float wave_sum(float v) {
    #pragma unroll
    for (int o = 32; o > 0; o >>= 1) v += __shfl_down(v, o, 64);
    return v;
}

// ---------------------------------------------------------------------------
// K1: normalize proj_weight rows, store TRANSPOSED k-major: wnt[k][j], fp32.
__global__ void k_norm_w(const float* __restrict__ w, float* __restrict__ wnt) {
    int j = blockIdx.x;
    int t = threadIdx.x;
    float4 v = ((const float4*)(w + (size_t)j * DIM))[t];
    float ss = v.x*v.x + v.y*v.y + v.z*v.z + v.w*v.w;
    ss = wave_sum(ss);
    __shared__ float red[4];
    if ((t & 63) == 0) red[t >> 6] = ss;
    __syncthreads();
    float rn = 1.0f / fmaxf(sqrtf(red[0] + red[1] + red[2] + red[3]), 1e-12f);
    int k = t * 4;
    wnt[(size_t)(k+0)*NPROJ + j] = v.x * rn;
    wnt[(size_t)(k+1)*NPROJ + j] = v.y * rn;
    wnt[(size_t)(k+2)*NPROJ + j] = v.z * rn;
    wnt[(size_t)(k+3)*NPROJ + j] = v.w * rn;
}

// ---------------------------------------------------------------------------
// K2: emb_weight fp32 -> bf16.
__global__ void k_cvt(const float* __restrict__ s, u16* __restrict__ d) {
    int i = blockIdx.x * 256 + threadIdx.x;
    float4 v = ((const float4*)s)[i];
    ushort4 o; o.x = f2bf(v.x); o.y = f2bf(v.y); o.z = f2bf(v.z); o.w = f2bf(v.w);
    ((ushort4*)d)[i] = o;
}

// ---------------------------------------------------------------------------
// K3 fused front-end, v2: BOTH x and w tiles staged in LDS (round-2's direct
// global w reads were a dependent-load-latency disaster: VALUBusy 12%).
// Block = 128 threads (2 waves) = 64 rows x 64 j. Thread = 2 rows x 16 j.
// Grid = 512 -> 2 blocks/CU (LDS 38KB) -> 2 waves/SIMD for latency hiding.
// Per k per thread: 2 ds_read_b32 (x, bcast, pad-65 conflict-free) +
// 4 ds_read_b128 (w, 16-way bcast, 2-way banks = free) + 36 FMA -> VALU-bound.
// Row ss accumulated inline from x regs; RBF/top4/norm epilogue fused.
__global__ __launch_bounds__(128) void k_front(
        const float* __restrict__ x, const float* __restrict__ wnt,
        const float* __restrict__ mean, u16* __restrict__ z) {
    __shared__ float xs[64][65];    // [row][k], pad 65: store & read conflict-free
    __shared__ float ws[64][64];    // [k][j]
    __shared__ float mlds[NPROJ][21];  // pad 21: read banks 21j+b all-distinct
    int t = threadIdx.x;
    int row0 = blockIdx.x * 64;
    int rg = t >> 2;                // 0..31 -> rows 2rg, 2rg+1
    int jset = t & 3;               // *16 j

    for (int i = t; i < FDIM; i += 128) mlds[i / NBINS][i % NBINS] = mean[i];

    float acc[2][16] = {};
    float ss0 = 0.f, ss1 = 0.f;

    for (int c = 0; c < 16; c++) {
        int k0 = c * 64;
        // stage x[row0..+63][k0..+63]: 1024 float4, 8/thread, coalesced
        #pragma unroll
        for (int p = 0; p < 8; p++) {
            int idx = t + p * 128;
            int r = idx >> 4, kq = (idx & 15) * 4;
            float4 v = *(const float4*)(x + (size_t)(row0 + r) * DIM + k0 + kq);
            float* d = &xs[r][kq];   // scalar stores: bank r+4kq+j -> 2-way (free)
            d[0] = v.x; d[1] = v.y; d[2] = v.z; d[3] = v.w;
        }
        // stage w[k0..+63][0..63]: 1024 float4, 8/thread, k-major = coalesced
        #pragma unroll
        for (int p = 0; p < 8; p++) {
            int idx = t + p * 128;
            int wk = idx >> 4, jq = (idx & 15) * 4;
            *(float4*)&ws[wk][jq] = *(const float4*)(wnt + (size_t)(k0 + wk) * NPROJ + jq);
        }
        __syncthreads();
        #pragma unroll 4
        for (int k = 0; k < 64; k++) {
            float x0 = xs[2 * rg][k];
            float x1 = xs[2 * rg + 1][k];
            const float4* wp = (const float4*)&ws[k][jset * 16];
            float wv[16];
            *(float4*)&wv[0]  = wp[0];
            *(float4*)&wv[4]  = wp[1];
            *(float4*)&wv[8]  = wp[2];
            *(float4*)&wv[12] = wp[3];
            ss0 += x0 * x0; ss1 += x1 * x1;
            #pragma unroll
            for (int u = 0; u < 16; u++) {
                acc[0][u] += x0 * wv[u];
                acc[1][u] += x1 * wv[u];
            }
        }
        __syncthreads();
    }

    float rn[2];
    rn[0] = 1.0f / fmaxf(sqrtf(ss0), 1e-12f);
    rn[1] = 1.0f / fmaxf(sqrtf(ss1), 1e-12f);

    #pragma unroll
    for (int i = 0; i < 2; i++) {
        size_t row = (size_t)row0 + 2 * rg + i;
        u32* zp = (u32*)(z + row * FDIM + jset * 16 * NBINS);  // 640B contig
        #pragma unroll
        for (int jj = 0; jj < 16; jj++) {
            int j = jset * 16 + jj;
            float pv = acc[i][jj] * rn[i];
            float act[NBINS];
            float top0 = -1e30f, top1 = -1e30f, top2 = -1e30f, top3 = -1e30f;
            #pragma unroll
            for (int b = 0; b < NBINS; b++) {
                float d = pv - mlds[j][b];
                float a = __expf(-50.0f * d * d);   // 0.5/sigma2 = 50
                act[b] = a;
                if (a > top3) {
                    if (a > top0)      { top3 = top2; top2 = top1; top1 = top0; top0 = a; }
                    else if (a > top1) { top3 = top2; top2 = top1; top1 = a; }
                    else if (a > top2) { top3 = top2; top2 = a; }
                    else               { top3 = a; }
                }
            }
            float ssq = 0.0f;
            #pragma unroll
            for (int b = 0; b < NBINS; b++) {
                float a = (act[b] >= top3) ? act[b] : 0.0f;   // keep ties
                act[b] = a;
                ssq += a * a;
            }
            float rn2 = 1.0f / fmaxf(sqrtf(ssq), 1e-12f);
            #pragma unroll
            for (int q = 0; q < 10; q++) {
                u32 lo = f2bf(act[2*q] * rn2);
                u32 hi = f2bf(act[2*q+1] * rn2);
                zp[jj * 10 + q] = lo | (hi << 16);
            }
        }
    }
}

// ---------------------------------------------------------------------------
// K4: GEMM2 bf16 MFMA (round-1 version verbatim — known 160 us):
// C[m][n] = sum_k A[m][k]*B[n][k]; 128x128 tile, BK=32, 4 waves 2x2,
// wave = 4x4 of 16x16x32 MFMA, global_load_lds width-16 staging.
__device__ __forceinline__ void gl_lds16(const void* g, void* l) {
    __builtin_amdgcn_global_load_lds(
        (const __attribute__((address_space(1))) void*)g,
        (__attribute__((address_space(3))) void*)l, 16, 0, 0);
}

__global__ __launch_bounds__(256) void k_gemm2(const u16* __restrict__ A,
                                               const u16* __restrict__ B,
                                               float* __restrict__ C) {
    const int K = FDIM, N = EDIM;
    __shared__ u16 As[128 * 32];
    __shared__ u16 Bs[128 * 32];
    int t = threadIdx.x;
    int lane = t & 63, wave = t >> 6;
    int bm = blockIdx.y * 128, bn = blockIdx.x * 128;
    int wm = (wave >> 1) * 64, wn = (wave & 1) * 64;
    int m16 = lane & 15, q = lane >> 4;

    f32x4 zero = {0.f, 0.f, 0.f, 0.f};
    f32x4 acc[4][4];
    #pragma unroll
    for (int i = 0; i < 4; i++)
        #pragma unroll
        for (int j = 0; j < 4; j++) acc[i][j] = zero;

    int sr = t >> 2;
    int sc = (t & 3) * 8;
    const u16* ga = A + (size_t)(bm + sr) * K + sc;
    const u16* gb = B + (size_t)(bn + sr) * K + sc;
    u16* la = &As[sr * 32 + sc];
    u16* lb = &Bs[sr * 32 + sc];

    for (int k0 = 0; k0 < K; k0 += 32) {
        gl_lds16(ga + k0,                 la);
        gl_lds16(ga + k0 + (size_t)64*K,  la + 64 * 32);
        gl_lds16(gb + k0,                 lb);
        gl_lds16(gb + k0 + (size_t)64*K,  lb + 64 * 32);
        __syncthreads();
        bf16x8 af[4], bfr[4];
        #pragma unroll
        for (int i = 0; i < 4; i++)
            af[i] = *(const bf16x8*)&As[(wm + i * 16 + m16) * 32 + q * 8];
        #pragma unroll
        for (int j = 0; j < 4; j++)
            bfr[j] = *(const bf16x8*)&Bs[(wn + j * 16 + m16) * 32 + q * 8];
        #pragma unroll
        for (int i = 0; i < 4; i++)
            #pragma unroll
            for (int j = 0; j < 4; j++)
                acc[i][j] = __builtin_amdgcn_mfma_f32_16x16x32_bf16(
                    af[i], bfr[j], acc[i][j], 0, 0, 0);
        __syncthreads();
    }
    // C/D layout: col = lane&15, row = q*4 + reg  [m89-verified]
    #pragma unroll
    for (int i = 0; i < 4; i++)
        #pragma unroll
        for (int j = 0; j < 4; j++)
            #pragma unroll
            for (int r = 0; r < 4; r++) {
                int row = bm + wm + i * 16 + q * 4 + r;
                int col = bn + wn + j * 16 + m16;
                C[(size_t)row * N + col] = acc[i][j][r];
            }
}

// ---------------------------------------------------------------------------
extern "C" void kernel_launch(void* const* d_in, const int* in_sizes, int n_in,
                              void* d_out, int out_size, void* d_ws, size_t ws_size,
                              hipStream_t stream) {
    const float* x    = (const float*)d_in[0];   // [32768][1024]
    const float* pw   = (const float*)d_in[1];   // [64][1024]
    const float* mean = (const float*)d_in[2];   // [64][20]
    const float* emb  = (const float*)d_in[3];   // [1024][1280]
    float* out = (float*)d_out;                  // [32768][1024] fp32

    char* ws = (char*)d_ws;
    u16*   z    = (u16*)(ws);                    // 83,886,080 B
    float* wnt  = (float*)(ws + 83886080);       //    262,144 B (k-major)
    u16*   embW = (u16*)(ws + 84148224);         //  2,621,440 B
    // total: 86,769,664 B

    k_norm_w<<<64, 256, 0, stream>>>(pw, wnt);
    k_cvt<<<(EDIM * FDIM / 4) / 256, 256, 0, stream>>>(emb, embW);
    k_front<<<M_ROWS / 64, 128, 0, stream>>>(x, wnt, mean, z);
    k_gemm2<<<dim3(EDIM / 128, M_ROWS / 128), 256, 0, stream>>>(z, embW, out);
}